// Round 22
// baseline (59.223 us; speedup 1.0000x reference)
//
#include <hip/hip_runtime.h>
#include <hip/hip_bf16.h>
#include <stdint.h>

#define S_SCALE 30.0f
#define A_QSCALE 2.70505320166681f  /* 30*log2(e)/16 : product scale = 30*log2(e) */
#define N_ROWS 8192
#define D_DIM 256
#define C_CLS 10000
#define NCB 16

typedef __attribute__((ext_vector_type(16))) float f32x16;
typedef __attribute__((ext_vector_type(8))) int i32x8;

static __device__ __forceinline__ void gl16(const void* g, void* l) {
  __builtin_amdgcn_global_load_lds(
      (const __attribute__((address_space(1))) void*)g,
      (__attribute__((address_space(3))) void*)l, 16, 0, 0);
}

// load one 32B/lane MX fragment stored half-split (two 16B-dense 1KB regions)
static __device__ __forceinline__ i32x8 ld32(const char* p) {
  union { i32x8 v; struct { int4 a, b; } s; } u;
  u.s.a = *(const int4*)p;
  u.s.b = *(const int4*)(p + 1024);
  return u.v;
}

// 32-lane col sum (within each 32-lane half): 4 DPP stages + 16-row pair merge.
static __device__ __forceinline__ float row_sum32(float v) {
  union { float f; int i; } u, w;
  u.f = v;
  w.i = __builtin_amdgcn_update_dpp(0, u.i, 0xB1, 0xF, 0xF, true);  u.f += w.f; // lane^1
  w.i = __builtin_amdgcn_update_dpp(0, u.i, 0x4E, 0xF, 0xF, true);  u.f += w.f; // lane^2
  w.i = __builtin_amdgcn_update_dpp(0, u.i, 0x141, 0xF, 0xF, true); u.f += w.f; // half-mirror
  w.i = __builtin_amdgcn_update_dpp(0, u.i, 0x140, 0xF, 0xF, true); u.f += w.f; // row-mirror
  u.f += __shfl_xor(u.f, 16, 64);                                               // 16-row pair
  return u.f;
}

// ---- fused prep (fp8 e4m3) into HALF-SPLIT 32x32x64 MX layouts (verbatim from
// r21 -- absmax 0.0 verified). A carries folded exp scale (30*log2e/16), W x16;
// fragment-product scale = 30*log2(e) so the GEMM acc is directly the exp2 arg.
// Fragment (c32|r32, kchunk): 2048 B = half0 (lane bytes 0-15, 16B-dense at
// lane*16) + half1 (bytes 16-31 at 1024+lane*16); lane holds row/col=(lane&31),
// k-section=(lane>>5). WbF8: [c32 0..319][kchunk 0..3]; cols >= C_CLS zero
// (exp2(0)=1, subtracted in k_loss1). xnb8: [panel 0..63][r32*4+kchunk] frags.
__global__ __launch_bounds__(256) void k_prep(const float* __restrict__ x,
                                              const float* __restrict__ W,
                                              const int* __restrict__ target,
                                              unsigned char* __restrict__ xnb8,
                                              unsigned char* __restrict__ WbF8,
                                              float* __restrict__ tgt) {
  if (blockIdx.x < 1280) {
    int gidx = blockIdx.x * 256 + threadIdx.x;   // 0..327679 = 320*16*64
    int lane = gidx & 63;
    int kc = (gidx >> 6) & 15;
    int c32 = gidx >> 10;
    int hi = lane >> 5;
    int col = c32 * 32 + (lane & 31);
    int k0 = kc * 16 + hi * 8;
    int r0 = 0, r1 = 0;
    if (col < C_CLS) {
      const float4 a = *(const float4*)(W + (size_t)col * D_DIM + k0);
      const float4 b = *(const float4*)(W + (size_t)col * D_DIM + k0 + 4);
      r0 = __builtin_amdgcn_cvt_pk_fp8_f32(a.x * 16.f, a.y * 16.f, 0, false);
      r0 = __builtin_amdgcn_cvt_pk_fp8_f32(a.z * 16.f, a.w * 16.f, r0, true);
      r1 = __builtin_amdgcn_cvt_pk_fp8_f32(b.x * 16.f, b.y * 16.f, 0, false);
      r1 = __builtin_amdgcn_cvt_pk_fp8_f32(b.z * 16.f, b.w * 16.f, r1, true);
    }
    int kchunk = kc >> 2;
    int lk = (kc >> 1) & 1;               // 32-k section
    int half = kc & 1;                    // 16B half of the lane's 32B
    int fl = (col & 31) + 32 * lk;
    size_t dst = (size_t)c32 * 8192 + (size_t)kchunk * 2048 +
                 (size_t)half * 1024 + (size_t)fl * 16 + hi * 8;
    *(int2*)(WbF8 + dst) = (int2){r0, r1};
  } else {
    int row = (blockIdx.x - 1280) * 4 + (threadIdx.x >> 6);
    int l = threadIdx.x & 63;
    const float4 v = *(const float4*)(x + (size_t)row * D_DIM + l * 4);
    float ss = v.x * v.x + v.y * v.y + v.z * v.z + v.w * v.w;
#pragma unroll
    for (int m = 1; m < 64; m <<= 1) ss += __shfl_xor(ss, m, 64);
    float rn = 1.0f / sqrtf(ss);
    float s8 = rn * A_QSCALE;
    int r0 = __builtin_amdgcn_cvt_pk_fp8_f32(v.x * s8, v.y * s8, 0, false);
    r0 = __builtin_amdgcn_cvt_pk_fp8_f32(v.z * s8, v.w * s8, r0, true);
    // this thread's 4 k-bytes: k0 = l*4
    int panel = row >> 7, r32 = (row >> 5) & 3;
    int kchunk = l >> 4;
    int lk = (l >> 3) & 1;
    int half = (l >> 2) & 1;
    int fl = (row & 31) + 32 * lk;
    size_t dst = (size_t)panel * 32768 + (size_t)(r32 * 4 + kchunk) * 2048 +
                 (size_t)half * 1024 + (size_t)fl * 16 + (l & 3) * 4;
    *(int*)(xnb8 + dst) = r0;
    // exact fp32 target logit
    int tc = target[row];
    const float4 b = *(const float4*)(W + (size_t)tc * D_DIM + l * 4);
    float s = v.x * b.x + v.y * b.y + v.z * b.z + v.w * b.w;
#pragma unroll
    for (int m = 1; m < 64; m <<= 1) s += __shfl_xor(s, m, 64);
    if (l == 0) tgt[row] = s * rn;
  }
}

// ------- barrier-free fused MX-fp8 GEMM (32x32x64) + exp-sum, 256-thr blocks ----
// 1024 blocks (64 br x 8 cg x 2 sub), 4 waves (2wr x 2wc), wave tile 64x64 =
// 2x2 frags of 32x32, block tile 128x128, 5 tiles of 128 cols.
// __launch_bounds__(256,2) -> 256-reg cap: acc 64 AGPR + B dbuf 32 VGPR +
// A 16 + addr ~ 137 regs, spill-PROOF (every MX attempt under 512-thr blocks'
// 128-cap spilled: r14 146MB, r21 55MB WRITE). 2 blocks/CU = 8 waves/CU.
// Per window: 2 B loads (prefetched 1 window ahead) + 2 A LDS reads + 4 MFMA
// x 68.7 cyc = 275 cyc matrix work -- per-wave duty ~40-70%, x2 waves/SIMD
// saturates the 2.3x-rate MX pipe. Layouts/numerics verified (r14/r15/r21).
__global__ __launch_bounds__(256, 2) void k_gemm(const unsigned char* __restrict__ xnb8,
                                                 const unsigned char* __restrict__ WbF8,
                                                 float* __restrict__ partials) {
  __shared__ __align__(16) char lds[33792];   // A frags 32 KB @0; rsum 1 KB @32768
  const int b = blockIdx.x;
  const int cg = b & 7;                        // XCD colgroup
  const int sub = (b >> 3) & 1;                // 640-col half
  const int br = b >> 4;                       // row panel 0..63 (128 rows)
  const int t = threadIdx.x;
  const int w = t >> 6, l = t & 63;
  const int wr = w >> 1, wc = w & 1;           // 2M x 2N waves (64x64 tile)
  float* rsumAll = (float*)(lds + 32768);      // [4 waves][64 rows]

  rsumAll[t] = 0.f;                            // covered by staging barrier

  // ---- stage A panel once: pure linear 32 KB copy into half-split frag LDS ----
  {
    const char* Ag = (const char*)xnb8 + (size_t)br * 32768;
#pragma unroll
    for (int i = 0; i < 8; ++i)
      gl16(Ag + i * 4096 + w * 1024 + l * 16, lds + i * 4096 + w * 1024);
    asm volatile("s_waitcnt vmcnt(0)" ::: "memory");
    __builtin_amdgcn_sched_barrier(0);
    __builtin_amdgcn_s_barrier();
  }

  f32x16 acc[2][2];
  const f32x16 z16 = (f32x16)(0.f);

  // A frag (r32 = wr*2+fm, kchunk) at lds + ((wr*2+fm)*4+kc)*2048, per-lane 16B
  const char* AwL = lds + (size_t)(wr * 2 * 4) * 2048 + (size_t)l * 16;
  // B base: c32 = (cg*2+sub)*20 + tt*4 + wc*2 + fn; frag stride 8192
  const char* Bw = (const char*)WbF8 + (size_t)((cg * 2 + sub) * 20 + wc * 2) * 8192 +
                   (size_t)l * 16;
  float* rw = rsumAll + w * 64;                // this wave's private rows

  // B double-buffer: p (even windows), q (odd windows)
  i32x8 pb0, pb1, qb0, qb1;
  pb0 = ld32(Bw);
  pb1 = ld32(Bw + 8192);

  for (int tt = 0; tt < 5; ++tt) {
    const char* Bt = Bw + (size_t)tt * 32768;  // 4 c32 * 8192 per 128-col tile

    auto windw = [&](int kc, bool first, i32x8& c0, i32x8& c1, i32x8& n0, i32x8& n1) {
      if (kc < 3) {
        n0 = ld32(Bt + (kc + 1) * 2048);
        n1 = ld32(Bt + 8192 + (kc + 1) * 2048);
      } else if (tt < 4) {
        // prefetch next tile's kchunk 0 under this tile's epilogue VALU
        n0 = ld32(Bt + 32768);
        n1 = ld32(Bt + 32768 + 8192);
      }
      i32x8 a0 = ld32(AwL + (0 * 4 + kc) * 2048);
      i32x8 a1 = ld32(AwL + (1 * 4 + kc) * 2048);
      __builtin_amdgcn_s_setprio(1);
      acc[0][0] = __builtin_amdgcn_mfma_scale_f32_32x32x64_f8f6f4(
          a0, c0, first ? z16 : acc[0][0], 0, 0, 0, 127, 0, 127);
      acc[0][1] = __builtin_amdgcn_mfma_scale_f32_32x32x64_f8f6f4(
          a0, c1, first ? z16 : acc[0][1], 0, 0, 0, 127, 0, 127);
      acc[1][0] = __builtin_amdgcn_mfma_scale_f32_32x32x64_f8f6f4(
          a1, c0, first ? z16 : acc[1][0], 0, 0, 0, 127, 0, 127);
      acc[1][1] = __builtin_amdgcn_mfma_scale_f32_32x32x64_f8f6f4(
          a1, c1, first ? z16 : acc[1][1], 0, 0, 0, 127, 0, 127);
      __builtin_amdgcn_s_setprio(0);
    };
    windw(0, true,  pb0, pb1, qb0, qb1);
    windw(1, false, qb0, qb1, pb0, pb1);
    windw(2, false, pb0, pb1, qb0, qb1);
    windw(3, false, qb0, qb1, pb0, pb1);
    // after window3: pb holds next tile's kchunk-0 frags (loads in flight)

    // ---- per-tile epilogue: exp2(acc) directly, 32-lane col-reduce, LDS rows ----
    // 32x32 C/D: col = lane&31, row = (j&3) + 8*(j>>2) + 4*(lane>>5). No mask:
    // padded cols contribute exp2(0)=1, removed as a constant in k_loss1.
#pragma unroll
    for (int fm = 0; fm < 2; ++fm) {
#pragma unroll
      for (int j = 0; j < 16; ++j) {
        float rs = __builtin_amdgcn_exp2f(acc[fm][0][j]) +
                   __builtin_amdgcn_exp2f(acc[fm][1][j]);
        rs = row_sum32(rs);
        if ((l & 31) == 0) {
          int row = fm * 32 + (j & 3) + 8 * (j >> 2) + 4 * (l >> 5);
          rw[row] += rs;
        }
      }
    }
  }

  // ---- final: combine 2 wc-waves per row, one coalesced store ----
  __syncthreads();
  if (t < 128) {
    int wr2 = t >> 6, r = t & 63;
    float sv = rsumAll[(wr2 * 2 + 0) * 64 + r] + rsumAll[(wr2 * 2 + 1) * 64 + r];
    partials[(size_t)(cg * 2 + sub) * N_ROWS + (size_t)br * 128 + t] = sv;
  }
}

// ---------------- per-row loss + block partial sums ----------------
__global__ __launch_bounds__(256) void k_loss1(const float* __restrict__ partials,
                                               const float* __restrict__ tgt,
                                               float* __restrict__ bsum) {
  __shared__ float wsum[4];
  int i = blockIdx.x * 256 + threadIdx.x;
  const float* p = partials + i;
  float s = -240.0f;   // remove padded cols 10000..10239 (W=0 -> exp term 1.0)
#pragma unroll
  for (int j = 0; j < NCB; ++j) s += p[(size_t)j * N_ROWS];
  float tl = tgt[i];
  float tcv = fminf(fmaxf(tl, -1.0f + 1e-7f), 1.0f - 1e-7f);
  const float cm = 0.95533648912560601964f;   // cos(0.3)
  const float sm = 0.29552020666133957510f;   // sin(0.3)
  float num = S_SCALE * (tcv * cm - sqrtf(fmaxf(1.0f - tcv * tcv, 0.f)) * sm);
  float sum_excl = s - __expf(S_SCALE * tl);
  float denom = __expf(num) + sum_excl;
  float L = num - __logf(denom);
#pragma unroll
  for (int m = 1; m < 64; m <<= 1) L += __shfl_xor(L, m, 64);
  int l = threadIdx.x & 63, w = threadIdx.x >> 6;
  if (l == 0) wsum[w] = L;
  __syncthreads();
  if (threadIdx.x == 0) bsum[blockIdx.x] = wsum[0] + wsum[1] + wsum[2] + wsum[3];
}

__global__ void k_loss2(const float* __restrict__ bsum, float* __restrict__ out) {
  float s = 0.f;
  for (int i = 0; i < 32; ++i) s += bsum[i];
  out[0] = -s / (float)N_ROWS;
}

// ---------------- launch ----------------
extern "C" void kernel_launch(void* const* d_in, const int* in_sizes, int n_in,
                              void* d_out, int out_size, void* d_ws, size_t ws_size,
                              hipStream_t stream) {
  const float* x = (const float*)d_in[0];
  const float* W = (const float*)d_in[1];
  const int* target = (const int*)d_in[2];
  float* out = (float*)d_out;
  char* ws = (char*)d_ws;

  unsigned char* xnb8 = (unsigned char*)(ws);               // 64*32768     = 2,097,152
  unsigned char* WbF8 = (unsigned char*)(ws + 2097152);     // 320*8192     = 2,621,440
  float* tgt = (float*)(ws + 4718592);                      // 8192*4
  float* partials = (float*)(ws + 4751360);                 // 16*8192*4    = 524,288
  float* bsum = (float*)(ws + 5275648);                     // 32*4

  k_prep<<<3328, 256, 0, stream>>>(x, W, target, xnb8, WbF8, tgt);
  k_gemm<<<1024, 256, 0, stream>>>(xnb8, WbF8, partials);
  k_loss1<<<32, 256, 0, stream>>>(partials, tgt, bsum);
  k_loss2<<<1, 1, 0, stream>>>(bsum, out);
}

// Round 23
// 44.210 us; speedup vs baseline: 1.3396x; 1.3396x over previous
//
#include <hip/hip_runtime.h>
#include <hip/hip_bf16.h>
#include <stdint.h>

#define S_SCALE 30.0f
#define XSC 360.0f                 /* A int8 scale (max|xn| ~ 0.39 w/ clamp) */
#define WSC 400.0f                 /* W int8 scale (max|W| ~ 0.26) */
#define SC_EPI 3.00561467e-4f      /* 30*log2(e) / (360*400) */
#define N_ROWS 8192
#define D_DIM 256
#define C_CLS 10000
#define NCB 8

typedef __attribute__((ext_vector_type(4))) int i32x4;

static __device__ __forceinline__ void gl16(const void* g, void* l) {
  __builtin_amdgcn_global_load_lds(
      (const __attribute__((address_space(1))) void*)g,
      (__attribute__((address_space(3))) void*)l, 16, 0, 0);
}

// quantize 4 floats (pre-scaled) to packed int8x4, clamp +-127, round-nearest
static __device__ __forceinline__ int q4(float a, float b, float c, float d) {
  int qa = (int)rintf(fminf(fmaxf(a, -127.f), 127.f));
  int qb = (int)rintf(fminf(fmaxf(b, -127.f), 127.f));
  int qc = (int)rintf(fminf(fmaxf(c, -127.f), 127.f));
  int qd = (int)rintf(fminf(fmaxf(d, -127.f), 127.f));
  return (qa & 255) | ((qb & 255) << 8) | ((qc & 255) << 16) | ((qd & 255) << 24);
}

// 16-lane (DPP-row) sum, VALU pipe only; all lanes receive the group sum.
static __device__ __forceinline__ float row_sum16(float v) {
  union { float f; int i; } u, w;
  u.f = v;
  w.i = __builtin_amdgcn_update_dpp(0, u.i, 0xB1, 0xF, 0xF, true);  u.f += w.f; // lane^1
  w.i = __builtin_amdgcn_update_dpp(0, u.i, 0x4E, 0xF, 0xF, true);  u.f += w.f; // lane^2
  w.i = __builtin_amdgcn_update_dpp(0, u.i, 0x141, 0xF, 0xF, true); u.f += w.f; // half-mirror
  w.i = __builtin_amdgcn_update_dpp(0, u.i, 0x140, 0xF, 0xF, true); u.f += w.f; // row-mirror
  return u.f;
}

// ---- fused prep (int8): blocks <1280 convert W (x400) to 16x16x64 frag layout;
// rest L2-normalize x (x360) into A-frag layout + exact fp32 target logit.
// WbF8: [c16 0..639][kchunk 0..3][lane]16B; lane=lk*16+lr holds
// W[col=c16*16+lr][k=kchunk*64+lk*16 ..+16] as int8; cols >= C_CLS zero
// (acc contribution 0 -> exp2(0)=1, subtracted in k_loss1).
// xnb8: [panel 0..63] 32KB: slot (r16*4+kchunk)*1024 + flane*16 + byte;
// row = panel*128 + r16*16 + lr, flane = lk*16+lr, k = kchunk*64+lk*16+byte.
__global__ __launch_bounds__(256) void k_prep(const float* __restrict__ x,
                                              const float* __restrict__ W,
                                              const int* __restrict__ target,
                                              unsigned char* __restrict__ xnb8,
                                              unsigned char* __restrict__ WbF8,
                                              float* __restrict__ tgt) {
  if (blockIdx.x < 1280) {
    int gidx = blockIdx.x * 256 + threadIdx.x;   // 0..327679 = 640*4*64*2
    int sub = gidx & 1;                          // which 8B half of lane's 16B
    int lane = (gidx >> 1) & 63;
    int kchunk = (gidx >> 7) & 3;
    int c16 = gidx >> 9;
    int col = c16 * 16 + (lane & 15);
    int k0 = kchunk * 64 + (lane >> 4) * 16 + sub * 8;
    int r0 = 0, r1 = 0;
    if (col < C_CLS) {
      const float4 a = *(const float4*)(W + (size_t)col * D_DIM + k0);
      const float4 b = *(const float4*)(W + (size_t)col * D_DIM + k0 + 4);
      r0 = q4(a.x * WSC, a.y * WSC, a.z * WSC, a.w * WSC);
      r1 = q4(b.x * WSC, b.y * WSC, b.z * WSC, b.w * WSC);
    }
    size_t dst = (size_t)c16 * 4096 + (size_t)kchunk * 1024 +
                 (size_t)lane * 16 + (size_t)sub * 8;
    *(int2*)(WbF8 + dst) = (int2){r0, r1};
  } else {
    int row = (blockIdx.x - 1280) * 4 + (threadIdx.x >> 6);
    int l = threadIdx.x & 63;
    const float4 v = *(const float4*)(x + (size_t)row * D_DIM + l * 4);
    float ss = v.x * v.x + v.y * v.y + v.z * v.z + v.w * v.w;
#pragma unroll
    for (int m = 1; m < 64; m <<= 1) ss += __shfl_xor(ss, m, 64);
    float rn = 1.0f / sqrtf(ss);
    float s8 = rn * XSC;
    int r0 = q4(v.x * s8, v.y * s8, v.z * s8, v.w * s8);
    // this thread's 4 k-bytes: k0 = l*4
    int panel = row >> 7, r16 = (row >> 4) & 7, lr = row & 15;
    int kchunk = l >> 4;
    int lk = (l >> 2) & 3;
    int byte = (l & 3) * 4;
    size_t dst = (size_t)panel * 32768 + (size_t)(r16 * 4 + kchunk) * 1024 +
                 (size_t)(lk * 16 + lr) * 16 + byte;
    *(int*)(xnb8 + dst) = r0;
    // exact fp32 target logit
    int tc = target[row];
    const float4 b = *(const float4*)(W + (size_t)tc * D_DIM + l * 4);
    float s = v.x * b.x + v.y * b.y + v.z * b.z + v.w * b.w;
#pragma unroll
    for (int m = 1; m < 64; m <<= 1) s += __shfl_xor(s, m, 64);
    if (l == 0) tgt[row] = s * rn;
  }
}

// ------- barrier-free fused i8 GEMM (16x16x64, 2x fp8 rate) + exp-sum -------
// r23 = r20's winning geometry (512 blocks 2/CU, 8 waves 2Mx4N, wave 64x64,
// A panel 32 KB staged once, 5 col-tiles) with the MFMA swapped to
// mfma_i32_16x16x64_i8: K=64/instruction -> MFMA floor halves (27->13.6 us/SIMD;
// 3944 TOPS ubench). int32 accumulation is EXACT; quant err ~3e-3/logit ->
// ~1e-3 on the loss. Frags are 16B/lane single-tuple loads (unlike MX's
// half-split 32B that drowned in v_movs). Registers mirror r20: acc 64 AGPR +
// B single-buffer 16 VGPR + A 4 + addr ~ 120 <= 128 cap (the never-spilled
// config). 4 windows/tile; B latency hidden by 4-wave TLP + epilogue overlap.
__global__ __launch_bounds__(512, 4) void k_gemm(const unsigned char* __restrict__ xnb8,
                                                 const unsigned char* __restrict__ WbF8,
                                                 float* __restrict__ partials) {
  __shared__ __align__(16) char lds[34816];   // A frags 32 KB @0; rsum 2 KB @32768
  const int b = blockIdx.x;
  const int cg = b & 7;                              // XCD colgroup 0..7
  const int br = b >> 3;                             // row panel 0..63 (128 rows)
  const int bc0 = cg * 5;                            // 5 consecutive 256-col tiles
  const int t = threadIdx.x;
  const int w = t >> 6, l = t & 63;
  const int wr = w >> 2, wc = w & 3;                 // 2M x 4N waves (64x64 tile)
  const int lr = l & 15, lk = l >> 4;
  float* rsumAll = (float*)(lds + 32768);            // [8 waves][64 rows]

  if (t < 512) rsumAll[t] = 0.f;                     // covered by staging barrier

  // ---- stage A panel once: pure linear 32 KB copy into frag-order LDS ----
  {
    const char* Ag = (const char*)xnb8 + (size_t)br * 32768;
#pragma unroll
    for (int i = 0; i < 4; ++i)
      gl16(Ag + i * 8192 + w * 1024 + l * 16, lds + i * 8192 + w * 1024);
    asm volatile("s_waitcnt vmcnt(0)" ::: "memory");
    __builtin_amdgcn_sched_barrier(0);
    __builtin_amdgcn_s_barrier();
  }

  i32x4 acc[4][4];
  const i32x4 zi = (i32x4){0, 0, 0, 0};

  // wave's A base in LDS (slot = (wr*4+fm)*4 + kc, 1024 B each), per-lane 16B
  const char* AwL = lds + (size_t)wr * 16384 + (size_t)l * 16;
  // wave's B base in global frag layout (c16 = bc*16 + wc*4 + fn), per-lane 16B
  const unsigned char* Bw = WbF8 + (size_t)(bc0 * 16 + wc * 4) * 4096 + (size_t)l * 16;
  float* rw = rsumAll + w * 64;                      // this wave's private rows

  for (int tt = 0; tt < 5; ++tt) {
    const unsigned char* Bt = Bw + (size_t)tt * 65536;  // 16 c16 * 4096 per tile

    auto windw = [&](int kc, bool first) {
      i32x4 bf[4];
#pragma unroll
      for (int fn = 0; fn < 4; ++fn)
        bf[fn] = *(const i32x4*)(Bt + fn * 4096 + kc * 1024);
      __builtin_amdgcn_s_setprio(1);
#pragma unroll
      for (int fm = 0; fm < 4; ++fm) {
        i32x4 a = *(const i32x4*)(AwL + (fm * 4 + kc) * 1024);
#pragma unroll
        for (int fn = 0; fn < 4; ++fn)
          acc[fm][fn] = __builtin_amdgcn_mfma_i32_16x16x64_i8(
              a, bf[fn], first ? zi : acc[fm][fn], 0, 0, 0);
      }
      __builtin_amdgcn_s_setprio(0);
    };
    windw(0, true); windw(1, false); windw(2, false); windw(3, false);

    // ---- per-tile epilogue: cvt+scale+exp2, DPP col-reduce, LDS rows ----
    // 16x16 C/D: col = lane&15, row = (lane>>4)*4 + j. No mask: padded cols
    // give acc=0 -> exp2(0)=1, removed as a constant in k_loss1.
#pragma unroll
    for (int m = 0; m < 4; ++m) {
      float rs0 = 0.f, rs1 = 0.f, rs2 = 0.f, rs3 = 0.f;
#pragma unroll
      for (int n = 0; n < 4; ++n) {
        rs0 += __builtin_amdgcn_exp2f((float)acc[m][n][0] * SC_EPI);
        rs1 += __builtin_amdgcn_exp2f((float)acc[m][n][1] * SC_EPI);
        rs2 += __builtin_amdgcn_exp2f((float)acc[m][n][2] * SC_EPI);
        rs3 += __builtin_amdgcn_exp2f((float)acc[m][n][3] * SC_EPI);
      }
      rs0 = row_sum16(rs0); rs1 = row_sum16(rs1);
      rs2 = row_sum16(rs2); rs3 = row_sum16(rs3);
      if (lr == 0) {
        int row = m * 16 + lk * 4;
        rw[row + 0] += rs0; rw[row + 1] += rs1;
        rw[row + 2] += rs2; rw[row + 3] += rs3;
      }
    }
  }

  // ---- final: combine 4 wc-waves per row, one coalesced store ----
  __syncthreads();
  if (t < 128) {
    int wr2 = t >> 6, r = t & 63;
    float sv = rsumAll[(wr2 * 4 + 0) * 64 + r] + rsumAll[(wr2 * 4 + 1) * 64 + r] +
               rsumAll[(wr2 * 4 + 2) * 64 + r] + rsumAll[(wr2 * 4 + 3) * 64 + r];
    partials[(size_t)cg * N_ROWS + (size_t)br * 128 + t] = sv;
  }
}

// ---------------- per-row loss + block partial sums ----------------
__global__ __launch_bounds__(256) void k_loss1(const float* __restrict__ partials,
                                               const float* __restrict__ tgt,
                                               float* __restrict__ bsum) {
  __shared__ float wsum[4];
  int i = blockIdx.x * 256 + threadIdx.x;
  const float* p = partials + i;
  float s = -240.0f;   // remove padded cols 10000..10239 (acc=0 -> exp term 1.0)
#pragma unroll
  for (int j = 0; j < NCB; ++j) s += p[(size_t)j * N_ROWS];
  float tl = tgt[i];
  float tcv = fminf(fmaxf(tl, -1.0f + 1e-7f), 1.0f - 1e-7f);
  const float cm = 0.95533648912560601964f;   // cos(0.3)
  const float sm = 0.29552020666133957510f;   // sin(0.3)
  float num = S_SCALE * (tcv * cm - sqrtf(fmaxf(1.0f - tcv * tcv, 0.f)) * sm);
  float sum_excl = s - __expf(S_SCALE * tl);
  float denom = __expf(num) + sum_excl;
  float L = num - __logf(denom);
#pragma unroll
  for (int m = 1; m < 64; m <<= 1) L += __shfl_xor(L, m, 64);
  int l = threadIdx.x & 63, w = threadIdx.x >> 6;
  if (l == 0) wsum[w] = L;
  __syncthreads();
  if (threadIdx.x == 0) bsum[blockIdx.x] = wsum[0] + wsum[1] + wsum[2] + wsum[3];
}

__global__ void k_loss2(const float* __restrict__ bsum, float* __restrict__ out) {
  float s = 0.f;
  for (int i = 0; i < 32; ++i) s += bsum[i];
  out[0] = -s / (float)N_ROWS;
}

// ---------------- launch ----------------
extern "C" void kernel_launch(void* const* d_in, const int* in_sizes, int n_in,
                              void* d_out, int out_size, void* d_ws, size_t ws_size,
                              hipStream_t stream) {
  const float* x = (const float*)d_in[0];
  const float* W = (const float*)d_in[1];
  const int* target = (const int*)d_in[2];
  float* out = (float*)d_out;
  char* ws = (char*)d_ws;

  unsigned char* xnb8 = (unsigned char*)(ws);               // 64*32768     = 2,097,152
  unsigned char* WbF8 = (unsigned char*)(ws + 2097152);     // 640*4096     = 2,621,440
  float* tgt = (float*)(ws + 4718592);                      // 8192*4
  float* partials = (float*)(ws + 4751360);                 // 8*8192*4     = 262,144
  float* bsum = (float*)(ws + 5013504);                     // 32*4

  k_prep<<<3328, 256, 0, stream>>>(x, W, target, xnb8, WbF8, tgt);
  k_gemm<<<512, 512, 0, stream>>>(xnb8, WbF8, partials);
  k_loss1<<<32, 256, 0, stream>>>(partials, tgt, bsum);
  k_loss2<<<1, 1, 0, stream>>>(bsum, out);
}